// Round 8
// baseline (359.450 us; speedup 1.0000x reference)
//
#include <hip/hip_runtime.h>
#include <math.h>

// RBF mixture: out[i] = sum_m w_m * exp(-(x_i-mu_m)^T C_m (x_i-mu_m)), C_m = G_m G_m^T
// N=32768, M=2048, D=32.
// Round 8: fix r7's scratch spill (512thr/launch_bounds(512,4) -> 64 arch
// VGPRs -> 32 MB spill). New config: 256 threads, 32-row A-tile (36.9 KB LDS)
// -> 4 blocks/CU = 16 waves/CU (4/SIMD) with per-wave state halved:
// acc[2][4] + af[2] + bf[4] fits the 128-reg cap. Everything else kept from
// r7 (in-kernel A-gen, per-m survivor buckets, exp2f survivor path).

#define NN 32768
#define MM 2048
#define DDIM 32
#define KSYM 576           // 528 triangle + 32 cross + 2 const + 14 pad = 18*32
#define ROWS 32            // i-rows per screen block
#define KSTEPS 18
#define SCREEN 120.0f
#define MCAP 2048          // per-m survivor list capacity (ushort entries)
#define FCAP 1000000       // fallback flat list capacity

typedef __attribute__((ext_vector_type(8))) short short8;
typedef __attribute__((ext_vector_type(4))) float floatx4;

__device__ __forceinline__ unsigned int to_bf16(float f) {
  union { float f; unsigned int u; } x; x.f = f;
  return (x.u + 0x7fffu + ((x.u >> 16) & 1u)) >> 16;   // RNE, finite inputs only
}

// compile-time slot -> (d,f) table for the packed symmetric layout
struct DFTab { unsigned char d[528]; unsigned char f[528]; };
constexpr DFTab make_df() {
  DFTab t{};
  int s = 0;
  for (int d = 0; d < 32; ++d)
    for (int f = d; f < 32; ++f) {
      t.d[s] = (unsigned char)d; t.f[s] = (unsigned char)f; ++s;
    }
  return t;
}
constexpr DFTab DFT = make_df();

// value of A[row][s] given the row's x values; s must be compile-time
__device__ __forceinline__ float slot_val(const float* v, int s) {
  if (s < 528) return v[DFT.d[s]] * v[DFT.f[s]];
  if (s < 560) return v[s - 528];
  if (s < 562) return 1.f;
  return 0.f;
}

// runtime slot -> (d,f) (build_b only)
__device__ __forceinline__ void slot_df(int s, int* dd, int* ff) {
  int d = 0, b = 0;
  while (b + (DDIM - d) <= s) { b += DDIM - d; ++d; }
  *dd = d; *ff = d + (s - b);
}

// ---------------------------------------------------------------------------
// Kernel 1: bf16 B-matrix [M][KSYM]:
//  [0,528): C_dd diag / 2*C_df offdiag (triangle, d-major); [528,560): -2*(C mu);
//  560: c_hi, 561: c_lo (c = mu^T C mu); [562,576): 0
// ---------------------------------------------------------------------------
__global__ __launch_bounds__(256) void build_b_kernel(
    const float* __restrict__ gamma, const float* __restrict__ means,
    unsigned short* __restrict__ Bm) {
  __shared__ float G[DDIM][DDIM + 1];
  __shared__ float C[DDIM][DDIM + 1];
  __shared__ float bv[DDIM];
  __shared__ float cc;
  const int m = blockIdx.x;
  const int t = threadIdx.x;
  const float* g = gamma + (size_t)m * DDIM * DDIM;
  for (int l = t; l < DDIM * DDIM; l += 256) G[l >> 5][l & 31] = g[l];
  __syncthreads();
  const float* mu = means + m * DDIM;
  for (int l = t; l < DDIM * DDIM; l += 256) {
    int d = l >> 5, f = l & 31;
    float c = 0.f;
#pragma unroll
    for (int e = 0; e < DDIM; ++e) c += G[d][e] * G[f][e];
    C[d][f] = c;
  }
  __syncthreads();
  if (t < DDIM) {
    float b = 0.f;
#pragma unroll
    for (int f = 0; f < DDIM; ++f) b += C[t][f] * mu[f];
    bv[t] = b;
  }
  __syncthreads();
  if (t == 0) {
    float c = 0.f;
#pragma unroll
    for (int d = 0; d < DDIM; ++d) c += bv[d] * mu[d];
    cc = c;
  }
  __syncthreads();
  unsigned short* brow = Bm + (size_t)m * KSYM;
  for (int s = t; s < KSYM; s += 256) {
    float val;
    if (s < 528) {
      int d, f; slot_df(s, &d, &f);
      val = (d == f) ? C[d][d] : 2.f * C[d][f];
    } else if (s < 560) {
      val = -2.f * bv[s - 528];
    } else if (s == 560) {
      val = cc;
    } else if (s == 561) {
      unsigned int hi = to_bf16(cc);
      union { unsigned int u; float f; } xh; xh.u = hi << 16;
      val = cc - xh.f;
    } else {
      val = 0.f;
    }
    brow[s] = (unsigned short)to_bf16(val);
  }
}

// ---------------------------------------------------------------------------
// Exact scalar path (fallback list only).
// ---------------------------------------------------------------------------
__device__ __noinline__ double survivor_contrib(
    int m, const float* __restrict__ gamma, const float* __restrict__ means,
    const float* __restrict__ weights, const float* __restrict__ xrow) {
  const float* mu = means + m * DDIM;
  float v[DDIM];
#pragma unroll
  for (int d = 0; d < DDIM; ++d) v[d] = xrow[d] - mu[d];
  const float* g = gamma + (size_t)m * DDIM * DDIM;
  float Dex = 0.f;
  for (int e = 0; e < DDIM; ++e) {
    float y = 0.f;
#pragma unroll
    for (int d = 0; d < DDIM; ++d) y += g[d * DDIM + e] * v[d];
    Dex += y * y;
  }
  float e2 = -Dex * 1.44269504088896340736f;
  float kf = floorf(e2);
  float mant = exp2f(e2 - kf);
  return ldexp((double)(weights[m] * mant), (int)kf);
}

// ---------------------------------------------------------------------------
// Kernel 3: bf16 MFMA screen. 256 threads (4 waves), 32-row A-tile generated
// in-kernel into 36.9 KB dynamic LDS (XOR chunk swizzle; 0 conflicts
// r3-r7). 4 blocks/CU -> 16 waves/CU (4/SIMD); per-wave regs: acc[2][4]
// (32 AGPR) + af[2] + bf[4] (~48) + addr fits the 128 cap -> no spill
// (r7 spilled 32 MB at 64 arch VGPRs). Wave w sweeps m-quads (g*4+w)*64,
// g=0..7; B frags global->VGPR (B = 2.3 MB, L2-resident).
// Frag layout (m89/m97): A/B [row=lane&15][k=quad*8+j]; C/D col=lane&15,
// row=quad*4+reg. Survivors -> per-m bucket lists; overflow -> flat list.
// ---------------------------------------------------------------------------
__global__ __launch_bounds__(256, 4) void screen_kernel(
    const float* __restrict__ x, const unsigned short* __restrict__ Bm,
    unsigned int* __restrict__ mcnt, unsigned short* __restrict__ mlist,
    unsigned int* __restrict__ flist, unsigned int* __restrict__ fcount) {
  extern __shared__ __align__(16) unsigned short As[];   // ROWS * KSYM
  const int t = threadIdx.x;
  const int i0 = blockIdx.x * ROWS;
  const int lane = t & 63, w = t >> 6;                   // w in [0,4)
  const int lrow = lane & 15, quad = lane >> 4;

  // ---- generate A tile into swizzled LDS: row r (32), slot-block j (8) ----
  {
    const int r = t >> 3, j = t & 7;
    float v[DDIM];
#pragma unroll
    for (int q = 0; q < 8; ++q)
      *(floatx4*)&v[q * 4] = *(const floatx4*)(x + (size_t)(i0 + r) * DDIM + q * 4);
#pragma unroll
    for (int jj = 0; jj < 8; ++jj) {
      if (j == jj) {
#pragma unroll
        for (int cc = 0; cc < 9; ++cc) {
          const int c = jj * 9 + cc;                     // 16B chunk index 0..71
          unsigned int uu[4];
#pragma unroll
          for (int q = 0; q < 4; ++q) {
            const int s0 = c * 8 + q * 2;
            uu[q] = to_bf16(slot_val(v, s0)) | (to_bf16(slot_val(v, s0 + 1)) << 16);
          }
          const int cs = (c & ~7) | ((c & 7) ^ (r & 7));
          uint4 o; o.x = uu[0]; o.y = uu[1]; o.z = uu[2]; o.w = uu[3];
          *(uint4*)&As[r * KSYM + cs * 8] = o;
        }
      }
    }
  }
  __syncthreads();

#pragma unroll 1
  for (int g = 0; g < 8; ++g) {
    const int m0 = (g * 4 + w) * 64;                    // this wave's m-quad base
    const unsigned short* bb0 = Bm + (size_t)(m0 +  0 + lrow) * KSYM + quad * 8;
    const unsigned short* bb1 = Bm + (size_t)(m0 + 16 + lrow) * KSYM + quad * 8;
    const unsigned short* bb2 = Bm + (size_t)(m0 + 32 + lrow) * KSYM + quad * 8;
    const unsigned short* bb3 = Bm + (size_t)(m0 + 48 + lrow) * KSYM + quad * 8;

    floatx4 acc[2][4] = {};                              // [ti][mj]
#pragma unroll
    for (int kk = 0; kk < KSTEPS; ++kk) {
      short8 bf[4];
      bf[0] = *(const short8*)(bb0 + kk * 32);
      bf[1] = *(const short8*)(bb1 + kk * 32);
      bf[2] = *(const short8*)(bb2 + kk * 32);
      bf[3] = *(const short8*)(bb3 + kk * 32);
      short8 af[2];
#pragma unroll
      for (int ti = 0; ti < 2; ++ti) {
        int rr = ti * 16 + lrow;
        int c = kk * 4 + quad;
        int cs = (c & ~7) | ((c & 7) ^ (rr & 7));
        af[ti] = *(const short8*)&As[rr * KSYM + cs * 8];
      }
#pragma unroll
      for (int ti = 0; ti < 2; ++ti)
#pragma unroll
        for (int mj = 0; mj < 4; ++mj)
          acc[ti][mj] = __builtin_amdgcn_mfma_f32_16x16x32_bf16(
              af[ti], bf[mj], acc[ti][mj], 0, 0, 0);
    }

    // screen & emit survivors (rare) into per-m buckets
#pragma unroll
    for (int ti = 0; ti < 2; ++ti)
#pragma unroll
      for (int mj = 0; mj < 4; ++mj)
#pragma unroll
        for (int r = 0; r < 4; ++r) {
          float Dt = acc[ti][mj][r];
          if (Dt < SCREEN) {
            int gi = i0 + ti * 16 + quad * 4 + r;
            int gm = m0 + mj * 16 + lrow;
            unsigned int idx = atomicAdd(&mcnt[gm], 1u);
            if (idx < MCAP) {
              mlist[(size_t)gm * MCAP + idx] = (unsigned short)gi;
            } else {
              unsigned int fi = atomicAdd(fcount, 1u);
              if (fi < FCAP)
                flist[fi] = ((unsigned int)gi << 11) | (unsigned int)gm;
            }
          }
        }
  }
}

// ---------------------------------------------------------------------------
// Kernel 4: per-m survivor processing. Block = m. G_m^T staged in LDS
// (broadcast-read). Exact fp32 D; exp via exp2f mantissa + ldexp into double.
// ---------------------------------------------------------------------------
__global__ __launch_bounds__(256) void survivor2_kernel(
    const unsigned int* __restrict__ mcnt, const unsigned short* __restrict__ mlist,
    const float* __restrict__ x, const float* __restrict__ gamma,
    const float* __restrict__ means, const float* __restrict__ weights,
    double* __restrict__ acc_out) {
  __shared__ float Gt[DDIM][DDIM + 1];   // Gt[e][d] = G[d][e]
  __shared__ float mu[DDIM];
  const int m = blockIdx.x;
  const int t = threadIdx.x;
  unsigned int cnt = mcnt[m];
  if (cnt > MCAP) cnt = MCAP;
  if (cnt == 0) return;
  const float* g = gamma + (size_t)m * DDIM * DDIM;
  for (int l = t; l < DDIM * DDIM; l += 256) Gt[l & 31][l >> 5] = g[l];
  if (t < DDIM) mu[t] = means[m * DDIM + t];
  __syncthreads();
  const float wm = weights[m];
  for (unsigned int s = t; s < cnt; s += 256) {
    int gi = mlist[(size_t)m * MCAP + s];
    float v[DDIM];
#pragma unroll
    for (int q = 0; q < 8; ++q) {
      floatx4 xv = *(const floatx4*)(x + (size_t)gi * DDIM + q * 4);
      v[q * 4 + 0] = xv.x - mu[q * 4 + 0];
      v[q * 4 + 1] = xv.y - mu[q * 4 + 1];
      v[q * 4 + 2] = xv.z - mu[q * 4 + 2];
      v[q * 4 + 3] = xv.w - mu[q * 4 + 3];
    }
    float Dex = 0.f;
#pragma unroll
    for (int e = 0; e < DDIM; ++e) {
      float y = 0.f;
#pragma unroll
      for (int d = 0; d < DDIM; ++d) y += Gt[e][d] * v[d];
      Dex += y * y;
    }
    float e2 = -Dex * 1.44269504088896340736f;
    float kf = floorf(e2);
    float mant = exp2f(e2 - kf);
    atomicAdd(&acc_out[gi], ldexp((double)(wm * mant), (int)kf));
  }
}

// ---------------------------------------------------------------------------
// Kernel 5: fallback flat list (bucket overflow only; normally empty).
// ---------------------------------------------------------------------------
__global__ __launch_bounds__(256) void survivor_fallback_kernel(
    const unsigned int* __restrict__ flist, const unsigned int* __restrict__ fcount,
    const float* __restrict__ x, const float* __restrict__ gamma,
    const float* __restrict__ means, const float* __restrict__ weights,
    double* __restrict__ acc_out) {
  unsigned int total = *fcount;
  if (total > FCAP) total = FCAP;
  for (unsigned int idx = blockIdx.x * 256 + threadIdx.x; idx < total;
       idx += gridDim.x * 256) {
    unsigned int p = flist[idx];
    int gi = (int)(p >> 11), gm = (int)(p & 2047u);
    double c = survivor_contrib(gm, gamma, means, weights, x + (size_t)gi * DDIM);
    atomicAdd(&acc_out[gi], c);
  }
}

__global__ __launch_bounds__(256) void finalize_kernel(
    const double* __restrict__ acc, float* __restrict__ out) {
  int i = blockIdx.x * 256 + threadIdx.x;
  out[i] = (float)acc[i];
}

extern "C" void kernel_launch(void* const* d_in, const int* in_sizes, int n_in,
                              void* d_out, int out_size, void* d_ws, size_t ws_size,
                              hipStream_t stream) {
  (void)in_sizes; (void)n_in; (void)out_size;
  const float* x       = (const float*)d_in[0];   // [N][32]
  const float* gamma   = (const float*)d_in[1];   // [M][32][32]
  const float* means   = (const float*)d_in[2];   // [M][32]
  const float* weights = (const float*)d_in[3];   // [M]

  char* p = (char*)d_ws;
  double* acc          = (double*)p;            p += (size_t)NN * 8;       // zeroed
  unsigned int* fcount = (unsigned int*)p;      p += 16;                   // zeroed
  unsigned int* mcnt   = (unsigned int*)p;      p += (size_t)MM * 4;       // zeroed
  unsigned short* mlist= (unsigned short*)p;    p += (size_t)MM * MCAP * 2;
  unsigned int* flist  = (unsigned int*)p;      p += (size_t)FCAP * 4;
  unsigned short* Bm   = (unsigned short*)p;    p += (size_t)MM * KSYM * 2;
  const size_t needed = (size_t)(p - (char*)d_ws);
  const size_t zero_bytes = (size_t)NN * 8 + 16 + (size_t)MM * 4;
  if (ws_size < needed) return;

  (void)hipFuncSetAttribute((const void*)screen_kernel,
                            hipFuncAttributeMaxDynamicSharedMemorySize,
                            ROWS * KSYM * 2);

  hipMemsetAsync(d_ws, 0, zero_bytes, stream);   // acc + fcount + mcnt
  hipLaunchKernelGGL(build_b_kernel, dim3(MM), dim3(256), 0, stream, gamma, means, Bm);
  hipLaunchKernelGGL(screen_kernel, dim3(NN / ROWS), dim3(256),
                     ROWS * KSYM * 2, stream,
                     x, Bm, mcnt, mlist, flist, fcount);
  hipLaunchKernelGGL(survivor2_kernel, dim3(MM), dim3(256), 0, stream,
                     mcnt, mlist, x, gamma, means, weights, acc);
  hipLaunchKernelGGL(survivor_fallback_kernel, dim3(256), dim3(256), 0, stream,
                     flist, fcount, x, gamma, means, weights, acc);
  hipLaunchKernelGGL(finalize_kernel, dim3(NN / 256), dim3(256), 0, stream,
                     acc, (float*)d_out);
}

// Round 9
// 234.353 us; speedup vs baseline: 1.5338x; 1.5338x over previous
//
#include <hip/hip_runtime.h>
#include <math.h>

// RBF mixture: out[i] = sum_m w_m * exp(-(x_i-mu_m)^T C_m (x_i-mu_m)), C_m = G_m G_m^T
// N=32768, M=2048, D=32.
// Round 9: back to the best screen shape (r6: ROWS=64, 256 thr, acc[4][4],
// 2 blocks/CU) + in-kernel A-gen (r7) + modulo-scheduled 6-deep register ring
// for B loads (static slot indices defeat the full-unroll CSE that killed
// r6's manual prefetch). Survivor path = r8 (per-m buckets, exp2f+ldexp).

#define NN 32768
#define MM 2048
#define DDIM 32
#define KSYM 576           // 528 triangle + 32 cross + 2 const + 14 pad = 18*32
#define ROWS 64            // i-rows per screen block
#define KSTEPS 18
#define PIPE 6             // B-ring depth (ksteps in flight)
#define SCREEN 120.0f
#define MCAP 2048          // per-m survivor list capacity (ushort entries)
#define FCAP 1000000       // fallback flat list capacity

typedef __attribute__((ext_vector_type(8))) short short8;
typedef __attribute__((ext_vector_type(4))) float floatx4;

__device__ __forceinline__ unsigned int to_bf16(float f) {
  union { float f; unsigned int u; } x; x.f = f;
  return (x.u + 0x7fffu + ((x.u >> 16) & 1u)) >> 16;   // RNE, finite inputs only
}

// compile-time slot -> (d,f) table for the packed symmetric layout
struct DFTab { unsigned char d[528]; unsigned char f[528]; };
constexpr DFTab make_df() {
  DFTab t{};
  int s = 0;
  for (int d = 0; d < 32; ++d)
    for (int f = d; f < 32; ++f) {
      t.d[s] = (unsigned char)d; t.f[s] = (unsigned char)f; ++s;
    }
  return t;
}
constexpr DFTab DFT = make_df();

// value of A[row][s] given the row's x values; s must be compile-time
__device__ __forceinline__ float slot_val(const float* v, int s) {
  if (s < 528) return v[DFT.d[s]] * v[DFT.f[s]];
  if (s < 560) return v[s - 528];
  if (s < 562) return 1.f;
  return 0.f;
}

// runtime slot -> (d,f) (build_b only)
__device__ __forceinline__ void slot_df(int s, int* dd, int* ff) {
  int d = 0, b = 0;
  while (b + (DDIM - d) <= s) { b += DDIM - d; ++d; }
  *dd = d; *ff = d + (s - b);
}

// ---------------------------------------------------------------------------
// Kernel 1: bf16 B-matrix [M][KSYM]:
//  [0,528): C_dd diag / 2*C_df offdiag (triangle, d-major); [528,560): -2*(C mu);
//  560: c_hi, 561: c_lo (c = mu^T C mu); [562,576): 0
// ---------------------------------------------------------------------------
__global__ __launch_bounds__(256) void build_b_kernel(
    const float* __restrict__ gamma, const float* __restrict__ means,
    unsigned short* __restrict__ Bm) {
  __shared__ float G[DDIM][DDIM + 1];
  __shared__ float C[DDIM][DDIM + 1];
  __shared__ float bv[DDIM];
  __shared__ float cc;
  const int m = blockIdx.x;
  const int t = threadIdx.x;
  const float* g = gamma + (size_t)m * DDIM * DDIM;
  for (int l = t; l < DDIM * DDIM; l += 256) G[l >> 5][l & 31] = g[l];
  __syncthreads();
  const float* mu = means + m * DDIM;
  for (int l = t; l < DDIM * DDIM; l += 256) {
    int d = l >> 5, f = l & 31;
    float c = 0.f;
#pragma unroll
    for (int e = 0; e < DDIM; ++e) c += G[d][e] * G[f][e];
    C[d][f] = c;
  }
  __syncthreads();
  if (t < DDIM) {
    float b = 0.f;
#pragma unroll
    for (int f = 0; f < DDIM; ++f) b += C[t][f] * mu[f];
    bv[t] = b;
  }
  __syncthreads();
  if (t == 0) {
    float c = 0.f;
#pragma unroll
    for (int d = 0; d < DDIM; ++d) c += bv[d] * mu[d];
    cc = c;
  }
  __syncthreads();
  unsigned short* brow = Bm + (size_t)m * KSYM;
  for (int s = t; s < KSYM; s += 256) {
    float val;
    if (s < 528) {
      int d, f; slot_df(s, &d, &f);
      val = (d == f) ? C[d][d] : 2.f * C[d][f];
    } else if (s < 560) {
      val = -2.f * bv[s - 528];
    } else if (s == 560) {
      val = cc;
    } else if (s == 561) {
      unsigned int hi = to_bf16(cc);
      union { unsigned int u; float f; } xh; xh.u = hi << 16;
      val = cc - xh.f;
    } else {
      val = 0.f;
    }
    brow[s] = (unsigned short)to_bf16(val);
  }
}

// ---------------------------------------------------------------------------
// Exact scalar path (fallback list only).
// ---------------------------------------------------------------------------
__device__ __noinline__ double survivor_contrib(
    int m, const float* __restrict__ gamma, const float* __restrict__ means,
    const float* __restrict__ weights, const float* __restrict__ xrow) {
  const float* mu = means + m * DDIM;
  float v[DDIM];
#pragma unroll
  for (int d = 0; d < DDIM; ++d) v[d] = xrow[d] - mu[d];
  const float* g = gamma + (size_t)m * DDIM * DDIM;
  float Dex = 0.f;
  for (int e = 0; e < DDIM; ++e) {
    float y = 0.f;
#pragma unroll
    for (int d = 0; d < DDIM; ++d) y += g[d * DDIM + e] * v[d];
    Dex += y * y;
  }
  float e2 = -Dex * 1.44269504088896340736f;
  float kf = floorf(e2);
  float mant = exp2f(e2 - kf);
  return ldexp((double)(weights[m] * mant), (int)kf);
}

// ---------------------------------------------------------------------------
// Kernel 3: bf16 MFMA screen. 256 threads (4 waves), 64-row A-tile generated
// in-kernel into 73.7 KB dynamic LDS (XOR chunk swizzle; 0 conflicts r3-r8).
// 2 blocks/CU (LDS-bound), launch_bounds(256,2) -> 256-reg budget.
// Wave w sweeps m-quads (g*4+w)*64, g=0..7. B loads modulo-scheduled:
// 6-deep static-slot register ring, prologue(6) / steady(2x6) / drain(6),
// so loads for kstep k+6 issue during kstep k's MFMAs (distinct addresses ->
// no CSE; ~24 loads in flight -> partial-vmcnt waits).
// Frag layout (m89/m97): A/B [row=lane&15][k=quad*8+j]; C/D col=lane&15,
// row=quad*4+reg. Survivors -> per-m bucket lists; overflow -> flat list.
// ---------------------------------------------------------------------------
__global__ __launch_bounds__(256, 2) void screen_kernel(
    const float* __restrict__ x, const unsigned short* __restrict__ Bm,
    unsigned int* __restrict__ mcnt, unsigned short* __restrict__ mlist,
    unsigned int* __restrict__ flist, unsigned int* __restrict__ fcount) {
  extern __shared__ __align__(16) unsigned short As[];   // ROWS * KSYM
  const int t = threadIdx.x;
  const int i0 = blockIdx.x * ROWS;
  const int lane = t & 63, w = t >> 6;                   // w in [0,4)
  const int lrow = lane & 15, quad = lane >> 4;

  // ---- generate A tile into swizzled LDS: row r (64), chunk-quarter j (4) ----
  {
    const int r = t >> 2, j = t & 3;
    float v[DDIM];
#pragma unroll
    for (int q = 0; q < 8; ++q)
      *(floatx4*)&v[q * 4] = *(const floatx4*)(x + (size_t)(i0 + r) * DDIM + q * 4);
#pragma unroll
    for (int jj = 0; jj < 4; ++jj) {
      if (j == jj) {
#pragma unroll
        for (int cc = 0; cc < 18; ++cc) {
          const int c = jj * 18 + cc;                    // 16B chunk index 0..71
          unsigned int uu[4];
#pragma unroll
          for (int q = 0; q < 4; ++q) {
            const int s0 = c * 8 + q * 2;
            uu[q] = to_bf16(slot_val(v, s0)) | (to_bf16(slot_val(v, s0 + 1)) << 16);
          }
          const int cs = (c & ~7) | ((c & 7) ^ (r & 7));
          uint4 o; o.x = uu[0]; o.y = uu[1]; o.z = uu[2]; o.w = uu[3];
          *(uint4*)&As[r * KSYM + cs * 8] = o;
        }
      }
    }
  }
  __syncthreads();

#pragma unroll 1
  for (int g = 0; g < 8; ++g) {
    const int m0 = (g * 4 + w) * 64;                    // this wave's m-quad base
    const unsigned short* bb0 = Bm + (size_t)(m0 +  0 + lrow) * KSYM + quad * 8;
    const unsigned short* bb1 = Bm + (size_t)(m0 + 16 + lrow) * KSYM + quad * 8;
    const unsigned short* bb2 = Bm + (size_t)(m0 + 32 + lrow) * KSYM + quad * 8;
    const unsigned short* bb3 = Bm + (size_t)(m0 + 48 + lrow) * KSYM + quad * 8;

    floatx4 acc[4][4] = {};                              // [ti][mj]
    short8 ring[PIPE][4];

    // prologue: ksteps 0..5 in flight
#pragma unroll
    for (int p = 0; p < PIPE; ++p) {
      ring[p][0] = *(const short8*)(bb0 + p * 32);
      ring[p][1] = *(const short8*)(bb1 + p * 32);
      ring[p][2] = *(const short8*)(bb2 + p * 32);
      ring[p][3] = *(const short8*)(bb3 + p * 32);
    }

    // steady: 2 groups of 6; compute kstep kb*6+u from slot u, refill slot u
    // with kstep kb*6+u+6 (always valid: max = 1*6+5+6 = 17)
#pragma unroll 1
    for (int kb = 0; kb < 2; ++kb) {
#pragma unroll
      for (int u = 0; u < PIPE; ++u) {
        const int kk = kb * PIPE + u;
        short8 af[4];
#pragma unroll
        for (int ti = 0; ti < 4; ++ti) {
          int rr = ti * 16 + lrow;
          int c = kk * 4 + quad;
          int cs = (c & ~7) | ((c & 7) ^ (rr & 7));
          af[ti] = *(const short8*)&As[rr * KSYM + cs * 8];
        }
#pragma unroll
        for (int ti = 0; ti < 4; ++ti)
#pragma unroll
          for (int mj = 0; mj < 4; ++mj)
            acc[ti][mj] = __builtin_amdgcn_mfma_f32_16x16x32_bf16(
                af[ti], ring[u][mj], acc[ti][mj], 0, 0, 0);
        const int kn = kk + PIPE;
        ring[u][0] = *(const short8*)(bb0 + kn * 32);
        ring[u][1] = *(const short8*)(bb1 + kn * 32);
        ring[u][2] = *(const short8*)(bb2 + kn * 32);
        ring[u][3] = *(const short8*)(bb3 + kn * 32);
      }
    }

    // drain: ksteps 12..17 from slots 0..5
#pragma unroll
    for (int u = 0; u < PIPE; ++u) {
      const int kk = 2 * PIPE + u;
      short8 af[4];
#pragma unroll
      for (int ti = 0; ti < 4; ++ti) {
        int rr = ti * 16 + lrow;
        int c = kk * 4 + quad;
        int cs = (c & ~7) | ((c & 7) ^ (rr & 7));
        af[ti] = *(const short8*)&As[rr * KSYM + cs * 8];
      }
#pragma unroll
      for (int ti = 0; ti < 4; ++ti)
#pragma unroll
        for (int mj = 0; mj < 4; ++mj)
          acc[ti][mj] = __builtin_amdgcn_mfma_f32_16x16x32_bf16(
              af[ti], ring[u][mj], acc[ti][mj], 0, 0, 0);
    }

    // screen & emit survivors (rare) into per-m buckets
#pragma unroll
    for (int ti = 0; ti < 4; ++ti)
#pragma unroll
      for (int mj = 0; mj < 4; ++mj)
#pragma unroll
        for (int r = 0; r < 4; ++r) {
          float Dt = acc[ti][mj][r];
          if (Dt < SCREEN) {
            int gi = i0 + ti * 16 + quad * 4 + r;
            int gm = m0 + mj * 16 + lrow;
            unsigned int idx = atomicAdd(&mcnt[gm], 1u);
            if (idx < MCAP) {
              mlist[(size_t)gm * MCAP + idx] = (unsigned short)gi;
            } else {
              unsigned int fi = atomicAdd(fcount, 1u);
              if (fi < FCAP)
                flist[fi] = ((unsigned int)gi << 11) | (unsigned int)gm;
            }
          }
        }
  }
}

// ---------------------------------------------------------------------------
// Kernel 4: per-m survivor processing. Block = m. G_m^T staged in LDS
// (broadcast-read). Exact fp32 D; exp via exp2f mantissa + ldexp into double.
// ---------------------------------------------------------------------------
__global__ __launch_bounds__(256) void survivor2_kernel(
    const unsigned int* __restrict__ mcnt, const unsigned short* __restrict__ mlist,
    const float* __restrict__ x, const float* __restrict__ gamma,
    const float* __restrict__ means, const float* __restrict__ weights,
    double* __restrict__ acc_out) {
  __shared__ float Gt[DDIM][DDIM + 1];   // Gt[e][d] = G[d][e]
  __shared__ float mu[DDIM];
  const int m = blockIdx.x;
  const int t = threadIdx.x;
  unsigned int cnt = mcnt[m];
  if (cnt > MCAP) cnt = MCAP;
  if (cnt == 0) return;
  const float* g = gamma + (size_t)m * DDIM * DDIM;
  for (int l = t; l < DDIM * DDIM; l += 256) Gt[l & 31][l >> 5] = g[l];
  if (t < DDIM) mu[t] = means[m * DDIM + t];
  __syncthreads();
  const float wm = weights[m];
  for (unsigned int s = t; s < cnt; s += 256) {
    int gi = mlist[(size_t)m * MCAP + s];
    float v[DDIM];
#pragma unroll
    for (int q = 0; q < 8; ++q) {
      floatx4 xv = *(const floatx4*)(x + (size_t)gi * DDIM + q * 4);
      v[q * 4 + 0] = xv.x - mu[q * 4 + 0];
      v[q * 4 + 1] = xv.y - mu[q * 4 + 1];
      v[q * 4 + 2] = xv.z - mu[q * 4 + 2];
      v[q * 4 + 3] = xv.w - mu[q * 4 + 3];
    }
    float Dex = 0.f;
#pragma unroll
    for (int e = 0; e < DDIM; ++e) {
      float y = 0.f;
#pragma unroll
      for (int d = 0; d < DDIM; ++d) y += Gt[e][d] * v[d];
      Dex += y * y;
    }
    float e2 = -Dex * 1.44269504088896340736f;
    float kf = floorf(e2);
    float mant = exp2f(e2 - kf);
    atomicAdd(&acc_out[gi], ldexp((double)(wm * mant), (int)kf));
  }
}

// ---------------------------------------------------------------------------
// Kernel 5: fallback flat list (bucket overflow only; normally empty).
// ---------------------------------------------------------------------------
__global__ __launch_bounds__(256) void survivor_fallback_kernel(
    const unsigned int* __restrict__ flist, const unsigned int* __restrict__ fcount,
    const float* __restrict__ x, const float* __restrict__ gamma,
    const float* __restrict__ means, const float* __restrict__ weights,
    double* __restrict__ acc_out) {
  unsigned int total = *fcount;
  if (total > FCAP) total = FCAP;
  for (unsigned int idx = blockIdx.x * 256 + threadIdx.x; idx < total;
       idx += gridDim.x * 256) {
    unsigned int p = flist[idx];
    int gi = (int)(p >> 11), gm = (int)(p & 2047u);
    double c = survivor_contrib(gm, gamma, means, weights, x + (size_t)gi * DDIM);
    atomicAdd(&acc_out[gi], c);
  }
}

__global__ __launch_bounds__(256) void finalize_kernel(
    const double* __restrict__ acc, float* __restrict__ out) {
  int i = blockIdx.x * 256 + threadIdx.x;
  out[i] = (float)acc[i];
}

extern "C" void kernel_launch(void* const* d_in, const int* in_sizes, int n_in,
                              void* d_out, int out_size, void* d_ws, size_t ws_size,
                              hipStream_t stream) {
  (void)in_sizes; (void)n_in; (void)out_size;
  const float* x       = (const float*)d_in[0];   // [N][32]
  const float* gamma   = (const float*)d_in[1];   // [M][32][32]
  const float* means   = (const float*)d_in[2];   // [M][32]
  const float* weights = (const float*)d_in[3];   // [M]

  char* p = (char*)d_ws;
  double* acc          = (double*)p;            p += (size_t)NN * 8;       // zeroed
  unsigned int* fcount = (unsigned int*)p;      p += 16;                   // zeroed
  unsigned int* mcnt   = (unsigned int*)p;      p += (size_t)MM * 4;       // zeroed
  unsigned short* mlist= (unsigned short*)p;    p += (size_t)MM * MCAP * 2;
  unsigned int* flist  = (unsigned int*)p;      p += (size_t)FCAP * 4;
  unsigned short* Bm   = (unsigned short*)p;    p += (size_t)MM * KSYM * 2;
  const size_t needed = (size_t)(p - (char*)d_ws);
  const size_t zero_bytes = (size_t)NN * 8 + 16 + (size_t)MM * 4;
  if (ws_size < needed) return;

  (void)hipFuncSetAttribute((const void*)screen_kernel,
                            hipFuncAttributeMaxDynamicSharedMemorySize,
                            ROWS * KSYM * 2);

  hipMemsetAsync(d_ws, 0, zero_bytes, stream);   // acc + fcount + mcnt
  hipLaunchKernelGGL(build_b_kernel, dim3(MM), dim3(256), 0, stream, gamma, means, Bm);
  hipLaunchKernelGGL(screen_kernel, dim3(NN / ROWS), dim3(256),
                     ROWS * KSYM * 2, stream,
                     x, Bm, mcnt, mlist, flist, fcount);
  hipLaunchKernelGGL(survivor2_kernel, dim3(MM), dim3(256), 0, stream,
                     mcnt, mlist, x, gamma, means, weights, acc);
  hipLaunchKernelGGL(survivor_fallback_kernel, dim3(256), dim3(256), 0, stream,
                     flist, fcount, x, gamma, means, weights, acc);
  hipLaunchKernelGGL(finalize_kernel, dim3(NN / 256), dim3(256), 0, stream,
                     acc, (float*)d_out);
}

// Round 10
// 185.609 us; speedup vs baseline: 1.9366x; 1.2626x over previous
//
#include <hip/hip_runtime.h>
#include <math.h>

// RBF mixture: out[i] = sum_m w_m * exp(-(x_i-mu_m)^T C_m (x_i-mu_m)), C_m = G_m G_m^T
// N=32768, M=2048, D=32.
// Round 10: amortize the per-kstep skeleton (4 B-loads + ds_reads + addr VALU)
// over 2x MFMA: ROWS=128, 512 thr (8 waves), 147 KB LDS A-tile (1 block/CU,
// 2 waves/SIMD -- same TLP as r9), acc[8][4]/wave -> 32 MFMA per kstep burst.
// B traffic halves (256 blocks x 2.36 MB). m-sweep rotated per block to
// spread L2. Survivor path unchanged (per-m buckets, exp2f+ldexp).

#define NN 32768
#define MM 2048
#define DDIM 32
#define KSYM 576           // 528 triangle + 32 cross + 2 const + 14 pad = 18*32
#define ROWS 128           // i-rows per screen block
#define KSTEPS 18
#define SCREEN 120.0f
#define MCAP 2048          // per-m survivor list capacity (ushort entries)
#define FCAP 1000000       // fallback flat list capacity

typedef __attribute__((ext_vector_type(8))) short short8;
typedef __attribute__((ext_vector_type(4))) float floatx4;

__device__ __forceinline__ unsigned int to_bf16(float f) {
  union { float f; unsigned int u; } x; x.f = f;
  return (x.u + 0x7fffu + ((x.u >> 16) & 1u)) >> 16;   // RNE, finite inputs only
}

// compile-time slot -> (d,f) table for the packed symmetric layout
struct DFTab { unsigned char d[528]; unsigned char f[528]; };
constexpr DFTab make_df() {
  DFTab t{};
  int s = 0;
  for (int d = 0; d < 32; ++d)
    for (int f = d; f < 32; ++f) {
      t.d[s] = (unsigned char)d; t.f[s] = (unsigned char)f; ++s;
    }
  return t;
}
constexpr DFTab DFT = make_df();

// value of A[row][s] given the row's x values; s must be compile-time
__device__ __forceinline__ float slot_val(const float* v, int s) {
  if (s < 528) return v[DFT.d[s]] * v[DFT.f[s]];
  if (s < 560) return v[s - 528];
  if (s < 562) return 1.f;
  return 0.f;
}

// runtime slot -> (d,f) (build_b only)
__device__ __forceinline__ void slot_df(int s, int* dd, int* ff) {
  int d = 0, b = 0;
  while (b + (DDIM - d) <= s) { b += DDIM - d; ++d; }
  *dd = d; *ff = d + (s - b);
}

// ---------------------------------------------------------------------------
// Kernel 1: bf16 B-matrix [M][KSYM]:
//  [0,528): C_dd diag / 2*C_df offdiag (triangle, d-major); [528,560): -2*(C mu);
//  560: c_hi, 561: c_lo (c = mu^T C mu); [562,576): 0
// ---------------------------------------------------------------------------
__global__ __launch_bounds__(256) void build_b_kernel(
    const float* __restrict__ gamma, const float* __restrict__ means,
    unsigned short* __restrict__ Bm) {
  __shared__ float G[DDIM][DDIM + 1];
  __shared__ float C[DDIM][DDIM + 1];
  __shared__ float bv[DDIM];
  __shared__ float cc;
  const int m = blockIdx.x;
  const int t = threadIdx.x;
  const float* g = gamma + (size_t)m * DDIM * DDIM;
  for (int l = t; l < DDIM * DDIM; l += 256) G[l >> 5][l & 31] = g[l];
  __syncthreads();
  const float* mu = means + m * DDIM;
  for (int l = t; l < DDIM * DDIM; l += 256) {
    int d = l >> 5, f = l & 31;
    float c = 0.f;
#pragma unroll
    for (int e = 0; e < DDIM; ++e) c += G[d][e] * G[f][e];
    C[d][f] = c;
  }
  __syncthreads();
  if (t < DDIM) {
    float b = 0.f;
#pragma unroll
    for (int f = 0; f < DDIM; ++f) b += C[t][f] * mu[f];
    bv[t] = b;
  }
  __syncthreads();
  if (t == 0) {
    float c = 0.f;
#pragma unroll
    for (int d = 0; d < DDIM; ++d) c += bv[d] * mu[d];
    cc = c;
  }
  __syncthreads();
  unsigned short* brow = Bm + (size_t)m * KSYM;
  for (int s = t; s < KSYM; s += 256) {
    float val;
    if (s < 528) {
      int d, f; slot_df(s, &d, &f);
      val = (d == f) ? C[d][d] : 2.f * C[d][f];
    } else if (s < 560) {
      val = -2.f * bv[s - 528];
    } else if (s == 560) {
      val = cc;
    } else if (s == 561) {
      unsigned int hi = to_bf16(cc);
      union { unsigned int u; float f; } xh; xh.u = hi << 16;
      val = cc - xh.f;
    } else {
      val = 0.f;
    }
    brow[s] = (unsigned short)to_bf16(val);
  }
}

// ---------------------------------------------------------------------------
// Exact scalar path (fallback list only).
// ---------------------------------------------------------------------------
__device__ __noinline__ double survivor_contrib(
    int m, const float* __restrict__ gamma, const float* __restrict__ means,
    const float* __restrict__ weights, const float* __restrict__ xrow) {
  const float* mu = means + m * DDIM;
  float v[DDIM];
#pragma unroll
  for (int d = 0; d < DDIM; ++d) v[d] = xrow[d] - mu[d];
  const float* g = gamma + (size_t)m * DDIM * DDIM;
  float Dex = 0.f;
  for (int e = 0; e < DDIM; ++e) {
    float y = 0.f;
#pragma unroll
    for (int d = 0; d < DDIM; ++d) y += g[d * DDIM + e] * v[d];
    Dex += y * y;
  }
  float e2 = -Dex * 1.44269504088896340736f;
  float kf = floorf(e2);
  float mant = exp2f(e2 - kf);
  return ldexp((double)(weights[m] * mant), (int)kf);
}

// ---------------------------------------------------------------------------
// Kernel 3: bf16 MFMA screen. 512 threads (8 waves), 128-row A-tile generated
// in-kernel into 147 KB dynamic LDS (XOR chunk swizzle; 0 conflicts r3-r9).
// 1 block/CU, 2 waves/SIMD, launch_bounds(512,2) -> 256 regs/wave:
// acc[8][4] (128) + af[8] (32) + bf[4] (16) + addr fits, no spill.
// Per kstep: 4 B-loads + 8 ds_reads + 32 MFMA -- skeleton cost per MFMA is
// half of r9's (the r6/r9 invariant 154us showed the skeleton binds).
// Wave w sweeps m-quads ((g*8+w)+rot)&31, g=0..3, rot=blockIdx&31 (L2 spread).
// Frag layout (m89/m97): A/B [row=lane&15][k=quad*8+j]; C/D col=lane&15,
// row=quad*4+reg. Survivors -> per-m bucket lists; overflow -> flat list.
// ---------------------------------------------------------------------------
__global__ __launch_bounds__(512, 2) void screen_kernel(
    const float* __restrict__ x, const unsigned short* __restrict__ Bm,
    unsigned int* __restrict__ mcnt, unsigned short* __restrict__ mlist,
    unsigned int* __restrict__ flist, unsigned int* __restrict__ fcount) {
  extern __shared__ __align__(16) unsigned short As[];   // ROWS * KSYM
  const int t = threadIdx.x;
  const int i0 = blockIdx.x * ROWS;
  const int lane = t & 63, w = t >> 6;                   // w in [0,8)
  const int lrow = lane & 15, quad = lane >> 4;
  const int rot = blockIdx.x & 31;

  // ---- generate A tile into swizzled LDS: row r (128), chunk-quarter j (4) ----
  {
    const int r = t >> 2, j = t & 3;
    float v[DDIM];
#pragma unroll
    for (int q = 0; q < 8; ++q)
      *(floatx4*)&v[q * 4] = *(const floatx4*)(x + (size_t)(i0 + r) * DDIM + q * 4);
#pragma unroll
    for (int jj = 0; jj < 4; ++jj) {
      if (j == jj) {
#pragma unroll
        for (int cc = 0; cc < 18; ++cc) {
          const int c = jj * 18 + cc;                    // 16B chunk index 0..71
          unsigned int uu[4];
#pragma unroll
          for (int q = 0; q < 4; ++q) {
            const int s0 = c * 8 + q * 2;
            uu[q] = to_bf16(slot_val(v, s0)) | (to_bf16(slot_val(v, s0 + 1)) << 16);
          }
          const int cs = (c & ~7) | ((c & 7) ^ (r & 7));
          uint4 o; o.x = uu[0]; o.y = uu[1]; o.z = uu[2]; o.w = uu[3];
          *(uint4*)&As[r * KSYM + cs * 8] = o;
        }
      }
    }
  }
  __syncthreads();

#pragma unroll 1
  for (int g = 0; g < 4; ++g) {
    const int mq = ((g * 8 + w) + rot) & 31;            // rotated m-quad index
    const int m0 = mq * 64;
    const unsigned short* bb0 = Bm + (size_t)(m0 +  0 + lrow) * KSYM + quad * 8;
    const unsigned short* bb1 = Bm + (size_t)(m0 + 16 + lrow) * KSYM + quad * 8;
    const unsigned short* bb2 = Bm + (size_t)(m0 + 32 + lrow) * KSYM + quad * 8;
    const unsigned short* bb3 = Bm + (size_t)(m0 + 48 + lrow) * KSYM + quad * 8;

    floatx4 acc[8][4] = {};                              // [ti][mj]
#pragma unroll
    for (int kk = 0; kk < KSTEPS; ++kk) {
      short8 bf[4];
      bf[0] = *(const short8*)(bb0 + kk * 32);
      bf[1] = *(const short8*)(bb1 + kk * 32);
      bf[2] = *(const short8*)(bb2 + kk * 32);
      bf[3] = *(const short8*)(bb3 + kk * 32);
      short8 af[8];
#pragma unroll
      for (int ti = 0; ti < 8; ++ti) {
        int rr = ti * 16 + lrow;
        int c = kk * 4 + quad;
        int cs = (c & ~7) | ((c & 7) ^ (rr & 7));
        af[ti] = *(const short8*)&As[rr * KSYM + cs * 8];
      }
#pragma unroll
      for (int ti = 0; ti < 8; ++ti)
#pragma unroll
        for (int mj = 0; mj < 4; ++mj)
          acc[ti][mj] = __builtin_amdgcn_mfma_f32_16x16x32_bf16(
              af[ti], bf[mj], acc[ti][mj], 0, 0, 0);
    }

    // screen & emit survivors (rare) into per-m buckets
#pragma unroll
    for (int ti = 0; ti < 8; ++ti)
#pragma unroll
      for (int mj = 0; mj < 4; ++mj)
#pragma unroll
        for (int r = 0; r < 4; ++r) {
          float Dt = acc[ti][mj][r];
          if (Dt < SCREEN) {
            int gi = i0 + ti * 16 + quad * 4 + r;
            int gm = m0 + mj * 16 + lrow;
            unsigned int idx = atomicAdd(&mcnt[gm], 1u);
            if (idx < MCAP) {
              mlist[(size_t)gm * MCAP + idx] = (unsigned short)gi;
            } else {
              unsigned int fi = atomicAdd(fcount, 1u);
              if (fi < FCAP)
                flist[fi] = ((unsigned int)gi << 11) | (unsigned int)gm;
            }
          }
        }
  }
}

// ---------------------------------------------------------------------------
// Kernel 4: per-m survivor processing. Block = m. G_m^T staged in LDS
// (broadcast-read). Exact fp32 D; exp via exp2f mantissa + ldexp into double.
// ---------------------------------------------------------------------------
__global__ __launch_bounds__(256) void survivor2_kernel(
    const unsigned int* __restrict__ mcnt, const unsigned short* __restrict__ mlist,
    const float* __restrict__ x, const float* __restrict__ gamma,
    const float* __restrict__ means, const float* __restrict__ weights,
    double* __restrict__ acc_out) {
  __shared__ float Gt[DDIM][DDIM + 1];   // Gt[e][d] = G[d][e]
  __shared__ float mu[DDIM];
  const int m = blockIdx.x;
  const int t = threadIdx.x;
  unsigned int cnt = mcnt[m];
  if (cnt > MCAP) cnt = MCAP;
  if (cnt == 0) return;
  const float* g = gamma + (size_t)m * DDIM * DDIM;
  for (int l = t; l < DDIM * DDIM; l += 256) Gt[l & 31][l >> 5] = g[l];
  if (t < DDIM) mu[t] = means[m * DDIM + t];
  __syncthreads();
  const float wm = weights[m];
  for (unsigned int s = t; s < cnt; s += 256) {
    int gi = mlist[(size_t)m * MCAP + s];
    float v[DDIM];
#pragma unroll
    for (int q = 0; q < 8; ++q) {
      floatx4 xv = *(const floatx4*)(x + (size_t)gi * DDIM + q * 4);
      v[q * 4 + 0] = xv.x - mu[q * 4 + 0];
      v[q * 4 + 1] = xv.y - mu[q * 4 + 1];
      v[q * 4 + 2] = xv.z - mu[q * 4 + 2];
      v[q * 4 + 3] = xv.w - mu[q * 4 + 3];
    }
    float Dex = 0.f;
#pragma unroll
    for (int e = 0; e < DDIM; ++e) {
      float y = 0.f;
#pragma unroll
      for (int d = 0; d < DDIM; ++d) y += Gt[e][d] * v[d];
      Dex += y * y;
    }
    float e2 = -Dex * 1.44269504088896340736f;
    float kf = floorf(e2);
    float mant = exp2f(e2 - kf);
    atomicAdd(&acc_out[gi], ldexp((double)(wm * mant), (int)kf));
  }
}

// ---------------------------------------------------------------------------
// Kernel 5: fallback flat list (bucket overflow only; normally empty).
// ---------------------------------------------------------------------------
__global__ __launch_bounds__(256) void survivor_fallback_kernel(
    const unsigned int* __restrict__ flist, const unsigned int* __restrict__ fcount,
    const float* __restrict__ x, const float* __restrict__ gamma,
    const float* __restrict__ means, const float* __restrict__ weights,
    double* __restrict__ acc_out) {
  unsigned int total = *fcount;
  if (total > FCAP) total = FCAP;
  for (unsigned int idx = blockIdx.x * 256 + threadIdx.x; idx < total;
       idx += gridDim.x * 256) {
    unsigned int p = flist[idx];
    int gi = (int)(p >> 11), gm = (int)(p & 2047u);
    double c = survivor_contrib(gm, gamma, means, weights, x + (size_t)gi * DDIM);
    atomicAdd(&acc_out[gi], c);
  }
}

__global__ __launch_bounds__(256) void finalize_kernel(
    const double* __restrict__ acc, float* __restrict__ out) {
  int i = blockIdx.x * 256 + threadIdx.x;
  out[i] = (float)acc[i];
}

extern "C" void kernel_launch(void* const* d_in, const int* in_sizes, int n_in,
                              void* d_out, int out_size, void* d_ws, size_t ws_size,
                              hipStream_t stream) {
  (void)in_sizes; (void)n_in; (void)out_size;
  const float* x       = (const float*)d_in[0];   // [N][32]
  const float* gamma   = (const float*)d_in[1];   // [M][32][32]
  const float* means   = (const float*)d_in[2];   // [M][32]
  const float* weights = (const float*)d_in[3];   // [M]

  char* p = (char*)d_ws;
  double* acc          = (double*)p;            p += (size_t)NN * 8;       // zeroed
  unsigned int* fcount = (unsigned int*)p;      p += 16;                   // zeroed
  unsigned int* mcnt   = (unsigned int*)p;      p += (size_t)MM * 4;       // zeroed
  unsigned short* mlist= (unsigned short*)p;    p += (size_t)MM * MCAP * 2;
  unsigned int* flist  = (unsigned int*)p;      p += (size_t)FCAP * 4;
  unsigned short* Bm   = (unsigned short*)p;    p += (size_t)MM * KSYM * 2;
  const size_t needed = (size_t)(p - (char*)d_ws);
  const size_t zero_bytes = (size_t)NN * 8 + 16 + (size_t)MM * 4;
  if (ws_size < needed) return;

  (void)hipFuncSetAttribute((const void*)screen_kernel,
                            hipFuncAttributeMaxDynamicSharedMemorySize,
                            ROWS * KSYM * 2);

  hipMemsetAsync(d_ws, 0, zero_bytes, stream);   // acc + fcount + mcnt
  hipLaunchKernelGGL(build_b_kernel, dim3(MM), dim3(256), 0, stream, gamma, means, Bm);
  hipLaunchKernelGGL(screen_kernel, dim3(NN / ROWS), dim3(512),
                     ROWS * KSYM * 2, stream,
                     x, Bm, mcnt, mlist, flist, fcount);
  hipLaunchKernelGGL(survivor2_kernel, dim3(MM), dim3(256), 0, stream,
                     mcnt, mlist, x, gamma, means, weights, acc);
  hipLaunchKernelGGL(survivor_fallback_kernel, dim3(256), dim3(256), 0, stream,
                     flist, fcount, x, gamma, means, weights, acc);
  hipLaunchKernelGGL(finalize_kernel, dim3(NN / 256), dim3(256), 0, stream,
                     acc, (float*)d_out);
}